// Round 13
// baseline (180.048 us; speedup 1.0000x reference)
//
#include <hip/hip_runtime.h>

#define LREL(x) ((x) > 0.0f ? (x) : 0.01f * (x))
#define LOG2E 1.44269504f

constexpr int NNODE = 78;
constexpr int GPB   = 8;             // graphs per block (lane dimension)
constexpr int ROWS  = 64;            // node-row streams per graph
constexpr int BLOCK = GPB * ROWS;    // 512 (8 waves)
constexpr int NI    = 2;             // node slots per thread
constexpr int NSLOT = ROWS * NI;     // 128
constexpr int PADS  = 17;            // padded lane stride (floats)

// ---------------------------------------------------------------------------
// Kernel 1: build slot-major CSR.
//  - rank nodes by degree (desc); round-robin rank->slot so each WAVE
//    (8 consecutive r-streams) gets ranks {w, w+8, w+16, ...} -> balanced
//  - each slot's edge list contiguous, 4-entry (16B) aligned
//  - entries are BYTE offsets into the [node][PADS] float feature array
// ---------------------------------------------------------------------------
__global__ void build_csr_kernel(const int* __restrict__ ei, int E,
                                 int* __restrict__ slot_node,
                                 int* __restrict__ slot_beg,   // [NSLOT+1]
                                 int* __restrict__ slot_cnt,
                                 int* __restrict__ csr2) {
    __shared__ int deg[NNODE];
    __shared__ int slot_of[NNODE];
    __shared__ int s2n[NSLOT];
    __shared__ int sbeg[NSLOT + 1];
    __shared__ int cur[NSLOT];
    int tid = threadIdx.x;
    if (tid < NNODE) deg[tid] = 0;
    if (tid < NSLOT) s2n[tid] = -1;
    __syncthreads();
    for (int e = tid; e < E; e += blockDim.x)
        atomicAdd(&deg[ei[E + e]], 1);                 // tgt = ei[1][e]
    __syncthreads();
    if (tid < NNODE) {
        int d = deg[tid], rk = 0;
        for (int m = 0; m < NNODE; ++m) {
            int dm = deg[m];
            rk += (dm > d) || (dm == d && m < tid);
        }
        // round-robin across waves: rank rk -> slot ((rk&7)<<3)|(rk>>3)
        int s;
        if (rk < 64) s = ((rk & 7) << 3) | (rk >> 3);
        else { int j = rk - 64; s = 64 + (((j & 7) << 3) | (j >> 3)); }
        slot_of[tid] = s;
    }
    __syncthreads();
    if (tid < NNODE) s2n[slot_of[tid]] = tid;
    __syncthreads();
    if (tid == 0) {
        int acc = 0;
        for (int s = 0; s < NSLOT; ++s) {
            sbeg[s] = acc;
            cur[s]  = acc;
            int n = s2n[s];
            int c = (n >= 0) ? deg[n] : 0;
            acc += (c + 3) & ~3;                       // 16B-align each region
        }
        sbeg[NSLOT] = acc;
    }
    __syncthreads();
    for (int e = tid; e < E; e += blockDim.x) {
        int t   = ei[E + e];
        int pos = atomicAdd(&cur[slot_of[t]], 1);
        csr2[pos] = ei[e] * (PADS * 4);                // byte offset of src row
    }
    if (tid < NSLOT) {
        int n = s2n[tid];
        slot_node[tid] = n;
        slot_beg[tid]  = sbeg[tid];
        slot_cnt[tid]  = (n >= 0) ? deg[n] : 0;
    }
    if (tid == 0) slot_beg[NSLOT] = sbeg[NSLOT];
}

// ---------------------------------------------------------------------------
// Kernel 2: LayerNorm(384) + Linear(384->20) + leaky. h[B,20] to workspace.
// ---------------------------------------------------------------------------
__global__ __launch_bounds__(256) void encode_kernel(
    const float* __restrict__ radio,
    const float* __restrict__ ln1g, const float* __restrict__ ln1b,
    const float* __restrict__ encw, const float* __restrict__ encb,
    int Bn, float* __restrict__ hout) {

    const int tid  = threadIdx.x;
    const int w    = tid >> 6;
    const int half = (tid >> 5) & 1;
    const int l32  = tid & 31;

    const float4* radio4 = (const float4*)radio;
    const float4* encw4  = (const float4*)encw;
    const float4* g14    = (const float4*)ln1g;
    const float4* b14    = (const float4*)ln1b;

    float4 xn0[3], xn1[3];
    const long g0 = (long)blockIdx.x * 16 + w * 4 + half;
    const long g1 = g0 + 2;

#pragma unroll
    for (int pp = 0; pp < 2; ++pp) {
        long gidx = pp ? g1 : g0;
        bool ok = gidx < Bn;
        float4* xn = pp ? xn1 : xn0;
        float s = 0.0f, q = 0.0f;
#pragma unroll
        for (int i = 0; i < 3; ++i) {
            float4 v = ok ? radio4[gidx * 96 + l32 + 32 * i]
                          : make_float4(0, 0, 0, 0);
            xn[i] = v;
            s += v.x + v.y + v.z + v.w;
            q += v.x * v.x + v.y * v.y + v.z * v.z + v.w * v.w;
        }
#pragma unroll
        for (int o = 16; o; o >>= 1) {
            s += __shfl_xor(s, o, 32);
            q += __shfl_xor(q, o, 32);
        }
        float mean = s * (1.0f / 384.0f);
        float var  = q * (1.0f / 384.0f) - mean * mean;
        float rstd = rsqrtf(var + 1e-5f);
#pragma unroll
        for (int i = 0; i < 3; ++i) {
            float4 gv = g14[l32 + 32 * i];
            float4 bv = b14[l32 + 32 * i];
            float4 v  = xn[i];
            v.x = (v.x - mean) * rstd * gv.x + bv.x;
            v.y = (v.y - mean) * rstd * gv.y + bv.y;
            v.z = (v.z - mean) * rstd * gv.z + bv.z;
            v.w = (v.w - mean) * rstd * gv.w + bv.w;
            xn[i] = v;
        }
    }

    float h0 = 0.0f, h1 = 0.0f;
    for (int j = 0; j < 20; ++j) {
        float4 w0 = encw4[j * 96 + l32];
        float4 w1 = encw4[j * 96 + l32 + 32];
        float4 w2 = encw4[j * 96 + l32 + 64];
#pragma unroll
        for (int pp = 0; pp < 2; ++pp) {
            const float4* xn = pp ? xn1 : xn0;
            float p = xn[0].x * w0.x;
            p = fmaf(xn[0].y, w0.y, p); p = fmaf(xn[0].z, w0.z, p);
            p = fmaf(xn[0].w, w0.w, p);
            p = fmaf(xn[1].x, w1.x, p); p = fmaf(xn[1].y, w1.y, p);
            p = fmaf(xn[1].z, w1.z, p); p = fmaf(xn[1].w, w1.w, p);
            p = fmaf(xn[2].x, w2.x, p); p = fmaf(xn[2].y, w2.y, p);
            p = fmaf(xn[2].z, w2.z, p); p = fmaf(xn[2].w, w2.w, p);
#pragma unroll
            for (int o = 16; o; o >>= 1) p += __shfl_xor(p, o, 32);
            if (pp) h1 = (l32 == j) ? p : h1;
            else    h0 = (l32 == j) ? p : h0;
        }
    }
    if (l32 < 20) {
        float eb = encb[l32];
        if (g0 < Bn) hout[g0 * 20 + l32] = LREL(h0 + eb);
        if (g1 < Bn) hout[g1 * 20 + l32] = LREL(h1 + eb);
    }
}

// ---------------------------------------------------------------------------
// Kernel 3: conv1 + conv2 + LN(78) + classifier. 8 graphs x 64 rows.
// 1024 blocks = 4 blocks/CU = 8 waves/SIMD (occupancy isolation test).
// ---------------------------------------------------------------------------
__global__ __launch_bounds__(BLOCK, 8) void graph_conv_kernel(
    const float* __restrict__ cli, const float* __restrict__ hin,
    const float* __restrict__ q1w, const float* __restrict__ q1b,
    const float* __restrict__ k1w, const float* __restrict__ k1b,
    const float* __restrict__ v1w, const float* __restrict__ v1b,
    const float* __restrict__ s1w, const float* __restrict__ s1b,
    const float* __restrict__ q2w, const float* __restrict__ q2b,
    const float* __restrict__ k2w, const float* __restrict__ k2b,
    const float* __restrict__ v2w, const float* __restrict__ v2b,
    const float* __restrict__ s2w, const float* __restrict__ s2b,
    const float* __restrict__ ln2g, const float* __restrict__ ln2b,
    const float* __restrict__ clsw, const float* __restrict__ clsb,
    const int* __restrict__ slot_node, const int* __restrict__ slot_beg,
    const int* __restrict__ slot_cnt, const int* __restrict__ csr2,
    int Bn, float* __restrict__ out) {

    __shared__ float  s_feat[NNODE * PADS];
    __shared__ float2 s_kv[NNODE * PADS];          // {k2*log2e, v2}
    __shared__ float  s_redA[8 * PADS];
    __shared__ float  s_redB[8 * PADS];
    __shared__ float  s_kwave[8 * PADS];           // per-wave max|k2L| partials
    __shared__ float  s_statM[GPB];
    __shared__ float  s_statR[GPB];
    __shared__ int    s_snode[NSLOT];
    __shared__ int    s_sbeg[NSLOT];
    __shared__ int    s_scnt[NSLOT];
    extern __shared__ int s_csr[];                 // slot-major, byte offsets

    const int tid  = threadIdx.x;
    const int g    = tid & 7;
    const int r    = tid >> 3;            // 0..63
    const int w    = tid >> 6;            // wave 0..7
    const int lane = tid & 63;
    const long base = (long)blockIdx.x * GPB;

    const int stot = slot_beg[NSLOT];
    for (int i = tid; i < stot; i += BLOCK) s_csr[i] = csr2[i];
    if (tid < NSLOT) {
        s_snode[tid] = slot_node[tid];
        s_sbeg[tid]  = slot_beg[tid];
        s_scnt[tid]  = slot_cnt[tid];
    }
    for (int idx = tid; idx < GPB * 58; idx += BLOCK) {
        int gg = idx / 58, c = idx - gg * 58;
        if (base + gg < Bn) s_feat[c * PADS + gg] = cli[(base + gg) * 58 + c];
    }
    if (tid < GPB * 20) {
        int gg = tid / 20, j = tid - gg * 20;
        if (base + gg < Bn) s_feat[(58 + j) * PADS + gg] = hin[(base + gg) * 20 + j];
    }

    const float Q1W0 = q1w[0], Q1W1 = q1w[1], Q1W2 = q1w[2], Q1W3 = q1w[3];
    const float Q1B0 = q1b[0], Q1B1 = q1b[1], Q1B2 = q1b[2], Q1B3 = q1b[3];
    const float K1L0 = k1w[0] * LOG2E, K1L1 = k1w[1] * LOG2E;
    const float K1L2 = k1w[2] * LOG2E, K1L3 = k1w[3] * LOG2E;
    const float V1W0 = v1w[0], V1W1 = v1w[1], V1W2 = v1w[2], V1W3 = v1w[3];
    const float V1B0 = v1b[0], V1B1 = v1b[1], V1B2 = v1b[2], V1B3 = v1b[3];
    const float S1W0 = s1w[0], S1W1 = s1w[1], S1W2 = s1w[2], S1W3 = s1w[3];
    const float S1B0 = s1b[0], S1B1 = s1b[1], S1B2 = s1b[2], S1B3 = s1b[3];
    const float Q2W0 = q2w[0], Q2W1 = q2w[1], Q2W2 = q2w[2], Q2W3 = q2w[3];
    const float K2W0 = k2w[0], K2W1 = k2w[1], K2W2 = k2w[2], K2W3 = k2w[3];
    const float V2W0 = v2w[0], V2W1 = v2w[1], V2W2 = v2w[2], V2W3 = v2w[3];
    const float S2W0 = s2w[0], S2W1 = s2w[1], S2W2 = s2w[2], S2W3 = s2w[3];
    const float Q2B = q2b[0], K2B = k2b[0], V2B = v2b[0], S2B = s2b[0];
    __syncthreads();

    const char* featg = (const char*)s_feat + g * 4;   // per-thread base
    const char* kvg   = (const char*)s_kv   + g * 8;

    int   nodes[NI];
    float y_q[NI], y_sk[NI], z[NI];
    float kmaxl = 0.0f;                   // local max |k2*log2e|

    // ---- TransformerConv 1 (H=4,C=1): single-pass softmax, quad-unrolled ----
#pragma unroll
    for (int k = 0; k < NI; ++k) {
        const int slot = k * ROWS + r;
        const int n    = s_snode[slot];
        const int cnt  = s_scnt[slot];
        const int ib   = s_sbeg[slot];
        nodes[k] = n;
        const bool act = n >= 0;
        const float xv = act ? s_feat[n * PADS + g] : 0.0f;
        float qh0 = fmaf(xv, Q1W0, Q1B0), qh1 = fmaf(xv, Q1W1, Q1B1);
        float qh2 = fmaf(xv, Q1W2, Q1B2), qh3 = fmaf(xv, Q1W3, Q1B3);
        float qa0 = qh0 * K1L0, qa1 = qh1 * K1L1;
        float qa2 = qh2 * K1L2, qa3 = qh3 * K1L3;
        float den0 = 0, den1 = 0, den2 = 0, den3 = 0;
        float wa0 = 0, wa1 = 0, wa2 = 0, wa3 = 0;
        const int nq = cnt >> 2;
        for (int t = 0; t < nq; ++t) {
            int4 c = *(const int4*)(s_csr + ib + (t << 2));
            float t0 = *(const float*)(featg + c.x);
            float t1 = *(const float*)(featg + c.y);
            float t2 = *(const float*)(featg + c.z);
            float t3 = *(const float*)(featg + c.w);
            float e00 = exp2f(qa0 * t0), e01 = exp2f(qa0 * t1),
                  e02 = exp2f(qa0 * t2), e03 = exp2f(qa0 * t3);
            float e10 = exp2f(qa1 * t0), e11 = exp2f(qa1 * t1),
                  e12 = exp2f(qa1 * t2), e13 = exp2f(qa1 * t3);
            float e20 = exp2f(qa2 * t0), e21 = exp2f(qa2 * t1),
                  e22 = exp2f(qa2 * t2), e23 = exp2f(qa2 * t3);
            float e30 = exp2f(qa3 * t0), e31 = exp2f(qa3 * t1),
                  e32 = exp2f(qa3 * t2), e33 = exp2f(qa3 * t3);
            den0 += (e00 + e01) + (e02 + e03);
            den1 += (e10 + e11) + (e12 + e13);
            den2 += (e20 + e21) + (e22 + e23);
            den3 += (e30 + e31) + (e32 + e33);
            wa0 = fmaf(e00, t0, fmaf(e01, t1, fmaf(e02, t2, fmaf(e03, t3, wa0))));
            wa1 = fmaf(e10, t0, fmaf(e11, t1, fmaf(e12, t2, fmaf(e13, t3, wa1))));
            wa2 = fmaf(e20, t0, fmaf(e21, t1, fmaf(e22, t2, fmaf(e23, t3, wa2))));
            wa3 = fmaf(e30, t0, fmaf(e31, t1, fmaf(e32, t2, fmaf(e33, t3, wa3))));
        }
        const int it = ib + (nq << 2), rem = cnt & 3;
        for (int j = 0; j < rem; ++j) {
            int cc = s_csr[it + j];
            float t0 = *(const float*)(featg + cc);
            float e0 = exp2f(qa0 * t0), e1 = exp2f(qa1 * t0);
            float e2 = exp2f(qa2 * t0), e3 = exp2f(qa3 * t0);
            den0 += e0; den1 += e1; den2 += e2; den3 += e3;
            wa0 = fmaf(e0, t0, wa0); wa1 = fmaf(e1, t0, wa1);
            wa2 = fmaf(e2, t0, wa2); wa3 = fmaf(e3, t0, wa3);
        }
        float y0 = LREL(fmaf(V1W0, wa0 / den0, V1B0) + fmaf(xv, S1W0, S1B0));
        float y1 = LREL(fmaf(V1W1, wa1 / den1, V1B1) + fmaf(xv, S1W1, S1B1));
        float y2 = LREL(fmaf(V1W2, wa2 / den2, V1B2) + fmaf(xv, S1W2, S1B2));
        float y3 = LREL(fmaf(V1W3, wa3 / den3, V1B3) + fmaf(xv, S1W3, S1B3));
        y_q[k]  = Q2B + y0 * Q2W0 + y1 * Q2W1 + y2 * Q2W2 + y3 * Q2W3;
        y_sk[k] = S2B + y0 * S2W0 + y1 * S2W1 + y2 * S2W2 + y3 * S2W3;
        if (act) {
            float k2v = K2B + y0 * K2W0 + y1 * K2W1 + y2 * K2W2 + y3 * K2W3;
            float v2v = V2B + y0 * V2W0 + y1 * V2W1 + y2 * V2W2 + y3 * V2W3;
            float k2L = k2v * LOG2E;
            s_kv[n * PADS + g] = make_float2(k2L, v2v);
            kmaxl = fmaxf(kmaxl, fabsf(k2L));
        }
    }
    // per-graph K-infinity (max |k2L| over 64 r-streams: wave then block)
    kmaxl = fmaxf(kmaxl, __shfl_xor(kmaxl, 8, 64));
    kmaxl = fmaxf(kmaxl, __shfl_xor(kmaxl, 16, 64));
    kmaxl = fmaxf(kmaxl, __shfl_xor(kmaxl, 32, 64));
    if (lane < 8) s_kwave[w * PADS + g] = kmaxl;
    __syncthreads();
    float kinf = 0.0f;
#pragma unroll
    for (int i = 0; i < 8; ++i) kinf = fmaxf(kinf, s_kwave[i * PADS + g]);

    // ---- TransformerConv 2 (H=1,C=1): single fused pass, shift = |q|*kinf ----
    float zs = 0, zq = 0;
#pragma unroll
    for (int k = 0; k < NI; ++k) {
        const int n = nodes[k];
        const int slot = k * ROWS + r;
        const int cnt  = s_scnt[slot];
        const int ib   = s_sbeg[slot];
        const bool act = n >= 0;
        const float q = y_q[k];
        float zz = 0.0f;
        if (act) {
            const float ml = fabsf(q) * kinf;     // upper bound: q*kvx <= ml
            const int nq = cnt >> 2, rem = cnt & 3;
            float den = 0, acc = 0;
            for (int t = 0; t < nq; ++t) {
                int4 c = *(const int4*)(s_csr + ib + (t << 2));
                float2 kv0 = *(const float2*)(kvg + (c.x << 1));
                float2 kv1 = *(const float2*)(kvg + (c.y << 1));
                float2 kv2 = *(const float2*)(kvg + (c.z << 1));
                float2 kv3 = *(const float2*)(kvg + (c.w << 1));
                float e0 = exp2f(fmaf(q, kv0.x, -ml));
                float e1 = exp2f(fmaf(q, kv1.x, -ml));
                float e2 = exp2f(fmaf(q, kv2.x, -ml));
                float e3 = exp2f(fmaf(q, kv3.x, -ml));
                den += (e0 + e1) + (e2 + e3);
                acc = fmaf(e0, kv0.y, fmaf(e1, kv1.y, fmaf(e2, kv2.y, fmaf(e3, kv3.y, acc))));
            }
            const int it = ib + (nq << 2);
            for (int j = 0; j < rem; ++j) {
                float2 kv0 = *(const float2*)(kvg + (s_csr[it + j] << 1));
                float e0 = exp2f(fmaf(q, kv0.x, -ml));
                den += e0;
                acc = fmaf(e0, kv0.y, acc);
            }
            zz = LREL(acc / den + y_sk[k]);
            zs += zz; zq = fmaf(zz, zz, zq);
        }
        z[k] = zz;
    }

    // ---- final LayerNorm(78) + classifier ----
    zs += __shfl_xor(zs, 8, 64); zs += __shfl_xor(zs, 16, 64); zs += __shfl_xor(zs, 32, 64);
    zq += __shfl_xor(zq, 8, 64); zq += __shfl_xor(zq, 16, 64); zq += __shfl_xor(zq, 32, 64);
    if (lane < 8) {
        s_redA[w * PADS + g] = zs;
        s_redB[w * PADS + g] = zq;
    }
    __syncthreads();
    if (tid < GPB) {
        float a = 0, bb = 0;
#pragma unroll
        for (int i = 0; i < 8; ++i) {
            a  += s_redA[i * PADS + tid];
            bb += s_redB[i * PADS + tid];
        }
        float mean = a * (1.0f / 78.0f);
        float var  = bb * (1.0f / 78.0f) - mean * mean;
        s_statM[tid] = mean;
        s_statR[tid] = rsqrtf(var + 1e-5f);
    }
    __syncthreads();
    float mean = s_statM[g], rstd = s_statR[g];
    float p0 = 0, p1 = 0;
#pragma unroll
    for (int k = 0; k < NI; ++k) {
        int n = nodes[k];
        if (n >= 0) {
            float zn = fmaf((z[k] - mean) * rstd, ln2g[n], ln2b[n]);
            p0 = fmaf(zn, clsw[n], p0);
            p1 = fmaf(zn, clsw[NNODE + n], p1);
        }
    }
    p0 += __shfl_xor(p0, 8, 64); p0 += __shfl_xor(p0, 16, 64); p0 += __shfl_xor(p0, 32, 64);
    p1 += __shfl_xor(p1, 8, 64); p1 += __shfl_xor(p1, 16, 64); p1 += __shfl_xor(p1, 32, 64);
    __syncthreads();
    if (lane < 8) {
        s_redA[w * PADS + g] = p0;
        s_redB[w * PADS + g] = p1;
    }
    __syncthreads();
    if (tid < GPB) {
        float a = 0, bb = 0;
#pragma unroll
        for (int i = 0; i < 8; ++i) {
            a  += s_redA[i * PADS + tid];
            bb += s_redB[i * PADS + tid];
        }
        long gi = base + tid;
        if (gi < Bn) {
            out[gi * 2 + 0] = a + clsb[0];
            out[gi * 2 + 1] = bb + clsb[1];
        }
    }
}

// ---------------------------------------------------------------------------
extern "C" void kernel_launch(void* const* d_in, const int* in_sizes, int n_in,
                              void* d_out, int out_size, void* d_ws, size_t ws_size,
                              hipStream_t stream) {
    const float* cli   = (const float*)d_in[0];
    const float* radio = (const float*)d_in[1];
    const int*   ei    = (const int*)d_in[2];
    const float* ln1g = (const float*)d_in[3];
    const float* ln1b = (const float*)d_in[4];
    const float* encw = (const float*)d_in[5];
    const float* encb = (const float*)d_in[6];
    const float* q1w  = (const float*)d_in[7];
    const float* q1b  = (const float*)d_in[8];
    const float* k1w  = (const float*)d_in[9];
    const float* k1b  = (const float*)d_in[10];
    const float* v1w  = (const float*)d_in[11];
    const float* v1b  = (const float*)d_in[12];
    const float* s1w  = (const float*)d_in[13];
    const float* s1b  = (const float*)d_in[14];
    const float* q2w  = (const float*)d_in[15];
    const float* q2b  = (const float*)d_in[16];
    const float* k2w  = (const float*)d_in[17];
    const float* k2b  = (const float*)d_in[18];
    const float* v2w  = (const float*)d_in[19];
    const float* v2b  = (const float*)d_in[20];
    const float* s2w  = (const float*)d_in[21];
    const float* s2b  = (const float*)d_in[22];
    const float* ln2g = (const float*)d_in[23];
    const float* ln2b = (const float*)d_in[24];
    const float* clsw = (const float*)d_in[25];
    const float* clsb = (const float*)d_in[26];

    const int E  = in_sizes[2] / 2;
    const int Bn = in_sizes[0] / 58;

    int* slot_node = (int*)d_ws;                  // 128
    int* slot_beg  = slot_node + 128;             // 129 (pad to 136)
    int* slot_cnt  = slot_beg + 136;              // 128
    int* csr2      = slot_cnt + 128;              // <= E + 3*NSLOT
    int  csr_cap   = E + 3 * NSLOT + 8;
    float* h       = (float*)(csr2 + ((csr_cap + 7) & ~7));

    build_csr_kernel<<<1, 256, 0, stream>>>(ei, E, slot_node, slot_beg,
                                            slot_cnt, csr2);

    const int egrid = (Bn + 15) / 16;
    encode_kernel<<<egrid, 256, 0, stream>>>(radio, ln1g, ln1b, encw, encb, Bn, h);

    const int grid = (Bn + GPB - 1) / GPB;
    size_t shmem = (size_t)csr_cap * sizeof(int);
    graph_conv_kernel<<<grid, BLOCK, shmem, stream>>>(
        cli, h,
        q1w, q1b, k1w, k1b, v1w, v1b, s1w, s1b,
        q2w, q2b, k2w, k2b, v2w, v2b, s2w, s2b,
        ln2g, ln2b, clsw, clsb,
        slot_node, slot_beg, slot_cnt, csr2, Bn, (float*)d_out);
}

// Round 14
// 164.596 us; speedup vs baseline: 1.0939x; 1.0939x over previous
//
#include <hip/hip_runtime.h>

#define LREL(x) ((x) > 0.0f ? (x) : 0.01f * (x))
#define LOG2E 1.44269504f

constexpr int NNODE = 78;
constexpr int GPB   = 32;            // graphs per block (lane dimension)
constexpr int ROWS  = 32;            // node-row streams per graph
constexpr int BLOCK = GPB * ROWS;    // 1024 (16 waves)
constexpr int NI    = 3;             // node slots per thread
constexpr int NSLOT = ROWS * NI;     // 96
constexpr int PADS  = 33;            // padded lane stride (floats)
constexpr int NWAVE = BLOCK / 64;    // 16

// ---------------------------------------------------------------------------
// Kernel 1: build slot-major CSR (same structure as R12; byte scale = PADS*4).
// ---------------------------------------------------------------------------
__global__ void build_csr_kernel(const int* __restrict__ ei, int E,
                                 int* __restrict__ slot_node,
                                 int* __restrict__ slot_beg,   // [NSLOT+1]
                                 int* __restrict__ slot_cnt,
                                 int* __restrict__ csr2) {
    __shared__ int deg[NNODE];
    __shared__ int slot_of[NNODE];
    __shared__ int s2n[NSLOT];
    __shared__ int sbeg[NSLOT + 1];
    __shared__ int cur[NSLOT];
    int tid = threadIdx.x;
    if (tid < NNODE) deg[tid] = 0;
    if (tid < NSLOT) s2n[tid] = -1;
    __syncthreads();
    for (int e = tid; e < E; e += blockDim.x)
        atomicAdd(&deg[ei[E + e]], 1);                 // tgt = ei[1][e]
    __syncthreads();
    if (tid < NNODE) {
        int d = deg[tid], rk = 0;
        for (int m = 0; m < NNODE; ++m) {
            int dm = deg[m];
            rk += (dm > d) || (dm == d && m < tid);
        }
        // serpentine: slots 0..31 <- ranks 0..31; 32..63 <- 63..32; 64..95 <- 64..95
        int s = (rk < 32) ? rk : ((rk < 64) ? (95 - rk) : rk);
        slot_of[tid] = s;
    }
    __syncthreads();
    if (tid < NNODE) s2n[slot_of[tid]] = tid;
    __syncthreads();
    if (tid == 0) {
        int acc = 0;
        for (int s = 0; s < NSLOT; ++s) {
            sbeg[s] = acc;
            cur[s]  = acc;
            int n = s2n[s];
            int c = (n >= 0) ? deg[n] : 0;
            acc += (c + 3) & ~3;                       // 16B-align each region
        }
        sbeg[NSLOT] = acc;
    }
    __syncthreads();
    for (int e = tid; e < E; e += blockDim.x) {
        int t   = ei[E + e];
        int pos = atomicAdd(&cur[slot_of[t]], 1);
        csr2[pos] = ei[e] * (PADS * 4);                // byte offset of src row
    }
    if (tid < NSLOT) {
        int n = s2n[tid];
        slot_node[tid] = n;
        slot_beg[tid]  = sbeg[tid];
        slot_cnt[tid]  = (n >= 0) ? deg[n] : 0;
    }
    if (tid == 0) slot_beg[NSLOT] = sbeg[NSLOT];
}

// ---------------------------------------------------------------------------
// Kernel 2: LayerNorm(384) + Linear(384->20) + leaky. h[B,20] to workspace.
// ---------------------------------------------------------------------------
__global__ __launch_bounds__(256) void encode_kernel(
    const float* __restrict__ radio,
    const float* __restrict__ ln1g, const float* __restrict__ ln1b,
    const float* __restrict__ encw, const float* __restrict__ encb,
    int Bn, float* __restrict__ hout) {

    const int tid  = threadIdx.x;
    const int w    = tid >> 6;
    const int half = (tid >> 5) & 1;
    const int l32  = tid & 31;

    const float4* radio4 = (const float4*)radio;
    const float4* encw4  = (const float4*)encw;
    const float4* g14    = (const float4*)ln1g;
    const float4* b14    = (const float4*)ln1b;

    float4 xn0[3], xn1[3];
    const long g0 = (long)blockIdx.x * 16 + w * 4 + half;
    const long g1 = g0 + 2;

#pragma unroll
    for (int pp = 0; pp < 2; ++pp) {
        long gidx = pp ? g1 : g0;
        bool ok = gidx < Bn;
        float4* xn = pp ? xn1 : xn0;
        float s = 0.0f, q = 0.0f;
#pragma unroll
        for (int i = 0; i < 3; ++i) {
            float4 v = ok ? radio4[gidx * 96 + l32 + 32 * i]
                          : make_float4(0, 0, 0, 0);
            xn[i] = v;
            s += v.x + v.y + v.z + v.w;
            q += v.x * v.x + v.y * v.y + v.z * v.z + v.w * v.w;
        }
#pragma unroll
        for (int o = 16; o; o >>= 1) {
            s += __shfl_xor(s, o, 32);
            q += __shfl_xor(q, o, 32);
        }
        float mean = s * (1.0f / 384.0f);
        float var  = q * (1.0f / 384.0f) - mean * mean;
        float rstd = rsqrtf(var + 1e-5f);
#pragma unroll
        for (int i = 0; i < 3; ++i) {
            float4 gv = g14[l32 + 32 * i];
            float4 bv = b14[l32 + 32 * i];
            float4 v  = xn[i];
            v.x = (v.x - mean) * rstd * gv.x + bv.x;
            v.y = (v.y - mean) * rstd * gv.y + bv.y;
            v.z = (v.z - mean) * rstd * gv.z + bv.z;
            v.w = (v.w - mean) * rstd * gv.w + bv.w;
            xn[i] = v;
        }
    }

    float h0 = 0.0f, h1 = 0.0f;
    for (int j = 0; j < 20; ++j) {
        float4 w0 = encw4[j * 96 + l32];
        float4 w1 = encw4[j * 96 + l32 + 32];
        float4 w2 = encw4[j * 96 + l32 + 64];
#pragma unroll
        for (int pp = 0; pp < 2; ++pp) {
            const float4* xn = pp ? xn1 : xn0;
            float p = xn[0].x * w0.x;
            p = fmaf(xn[0].y, w0.y, p); p = fmaf(xn[0].z, w0.z, p);
            p = fmaf(xn[0].w, w0.w, p);
            p = fmaf(xn[1].x, w1.x, p); p = fmaf(xn[1].y, w1.y, p);
            p = fmaf(xn[1].z, w1.z, p); p = fmaf(xn[1].w, w1.w, p);
            p = fmaf(xn[2].x, w2.x, p); p = fmaf(xn[2].y, w2.y, p);
            p = fmaf(xn[2].z, w2.z, p); p = fmaf(xn[2].w, w2.w, p);
#pragma unroll
            for (int o = 16; o; o >>= 1) p += __shfl_xor(p, o, 32);
            if (pp) h1 = (l32 == j) ? p : h1;
            else    h0 = (l32 == j) ? p : h0;
        }
    }
    if (l32 < 20) {
        float eb = encb[l32];
        if (g0 < Bn) hout[g0 * 20 + l32] = LREL(h0 + eb);
        if (g1 < Bn) hout[g1 * 20 + l32] = LREL(h1 + eb);
    }
}

// ---------------------------------------------------------------------------
// Kernel 3: conv1 + conv2 + LN(78) + classifier. 32 graphs x 32 rows.
// 256 blocks x 1024 thr = 1 block/CU, 16 waves/CU. Wave = 32 graphs x 2 rows.
// ---------------------------------------------------------------------------
__global__ __launch_bounds__(BLOCK, 4) void graph_conv_kernel(
    const float* __restrict__ cli, const float* __restrict__ hin,
    const float* __restrict__ q1w, const float* __restrict__ q1b,
    const float* __restrict__ k1w, const float* __restrict__ k1b,
    const float* __restrict__ v1w, const float* __restrict__ v1b,
    const float* __restrict__ s1w, const float* __restrict__ s1b,
    const float* __restrict__ q2w, const float* __restrict__ q2b,
    const float* __restrict__ k2w, const float* __restrict__ k2b,
    const float* __restrict__ v2w, const float* __restrict__ v2b,
    const float* __restrict__ s2w, const float* __restrict__ s2b,
    const float* __restrict__ ln2g, const float* __restrict__ ln2b,
    const float* __restrict__ clsw, const float* __restrict__ clsb,
    const int* __restrict__ slot_node, const int* __restrict__ slot_beg,
    const int* __restrict__ slot_cnt, const int* __restrict__ csr2,
    int Bn, float* __restrict__ out) {

    __shared__ float  s_feat[NNODE * PADS];
    __shared__ float2 s_kv[NNODE * PADS];          // {k2*log2e, v2}
    __shared__ float  s_redA[NWAVE * PADS];
    __shared__ float  s_redB[NWAVE * PADS];
    __shared__ float  s_kwave[NWAVE * PADS];       // per-wave max|k2L| partials
    __shared__ float  s_statM[GPB];
    __shared__ float  s_statR[GPB];
    __shared__ int    s_snode[NSLOT];
    __shared__ int    s_sbeg[NSLOT];
    __shared__ int    s_scnt[NSLOT];
    extern __shared__ int s_csr[];                 // slot-major, byte offsets

    const int tid  = threadIdx.x;
    const int g    = tid & 31;
    const int r    = tid >> 5;            // 0..31
    const int w    = tid >> 6;            // wave 0..15
    const int lane = tid & 63;
    const long base = (long)blockIdx.x * GPB;

    const int stot = slot_beg[NSLOT];
    for (int i = tid; i < stot; i += BLOCK) s_csr[i] = csr2[i];
    if (tid < NSLOT) {
        s_snode[tid] = slot_node[tid];
        s_sbeg[tid]  = slot_beg[tid];
        s_scnt[tid]  = slot_cnt[tid];
    }
    for (int idx = tid; idx < GPB * 58; idx += BLOCK) {
        int gg = idx / 58, c = idx - gg * 58;
        if (base + gg < Bn) s_feat[c * PADS + gg] = cli[(base + gg) * 58 + c];
    }
    if (tid < GPB * 20) {
        int gg = tid / 20, j = tid - gg * 20;
        if (base + gg < Bn) s_feat[(58 + j) * PADS + gg] = hin[(base + gg) * 20 + j];
    }

    const float Q1W0 = q1w[0], Q1W1 = q1w[1], Q1W2 = q1w[2], Q1W3 = q1w[3];
    const float Q1B0 = q1b[0], Q1B1 = q1b[1], Q1B2 = q1b[2], Q1B3 = q1b[3];
    const float K1L0 = k1w[0] * LOG2E, K1L1 = k1w[1] * LOG2E;
    const float K1L2 = k1w[2] * LOG2E, K1L3 = k1w[3] * LOG2E;
    const float V1W0 = v1w[0], V1W1 = v1w[1], V1W2 = v1w[2], V1W3 = v1w[3];
    const float V1B0 = v1b[0], V1B1 = v1b[1], V1B2 = v1b[2], V1B3 = v1b[3];
    const float S1W0 = s1w[0], S1W1 = s1w[1], S1W2 = s1w[2], S1W3 = s1w[3];
    const float S1B0 = s1b[0], S1B1 = s1b[1], S1B2 = s1b[2], S1B3 = s1b[3];
    const float Q2W0 = q2w[0], Q2W1 = q2w[1], Q2W2 = q2w[2], Q2W3 = q2w[3];
    const float K2W0 = k2w[0], K2W1 = k2w[1], K2W2 = k2w[2], K2W3 = k2w[3];
    const float V2W0 = v2w[0], V2W1 = v2w[1], V2W2 = v2w[2], V2W3 = v2w[3];
    const float S2W0 = s2w[0], S2W1 = s2w[1], S2W2 = s2w[2], S2W3 = s2w[3];
    const float Q2B = q2b[0], K2B = k2b[0], V2B = v2b[0], S2B = s2b[0];
    __syncthreads();

    const char* featg = (const char*)s_feat + g * 4;   // per-thread base
    const char* kvg   = (const char*)s_kv   + g * 8;

    int   nodes[NI];
    float y_q[NI], y_sk[NI], z[NI];
    float kmaxl = 0.0f;                   // local max |k2*log2e|

    // ---- TransformerConv 1 (H=4,C=1): single-pass softmax, quad-unrolled ----
#pragma unroll
    for (int k = 0; k < NI; ++k) {
        const int slot = k * ROWS + r;
        const int n    = s_snode[slot];
        const int cnt  = s_scnt[slot];
        const int ib   = s_sbeg[slot];
        nodes[k] = n;
        const bool act = n >= 0;
        const float xv = act ? s_feat[n * PADS + g] : 0.0f;
        float qh0 = fmaf(xv, Q1W0, Q1B0), qh1 = fmaf(xv, Q1W1, Q1B1);
        float qh2 = fmaf(xv, Q1W2, Q1B2), qh3 = fmaf(xv, Q1W3, Q1B3);
        float qa0 = qh0 * K1L0, qa1 = qh1 * K1L1;
        float qa2 = qh2 * K1L2, qa3 = qh3 * K1L3;
        float den0 = 0, den1 = 0, den2 = 0, den3 = 0;
        float wa0 = 0, wa1 = 0, wa2 = 0, wa3 = 0;
        const int nq = cnt >> 2;
        for (int t = 0; t < nq; ++t) {
            int4 c = *(const int4*)(s_csr + ib + (t << 2));
            float t0 = *(const float*)(featg + c.x);
            float t1 = *(const float*)(featg + c.y);
            float t2 = *(const float*)(featg + c.z);
            float t3 = *(const float*)(featg + c.w);
            float e00 = exp2f(qa0 * t0), e01 = exp2f(qa0 * t1),
                  e02 = exp2f(qa0 * t2), e03 = exp2f(qa0 * t3);
            float e10 = exp2f(qa1 * t0), e11 = exp2f(qa1 * t1),
                  e12 = exp2f(qa1 * t2), e13 = exp2f(qa1 * t3);
            float e20 = exp2f(qa2 * t0), e21 = exp2f(qa2 * t1),
                  e22 = exp2f(qa2 * t2), e23 = exp2f(qa2 * t3);
            float e30 = exp2f(qa3 * t0), e31 = exp2f(qa3 * t1),
                  e32 = exp2f(qa3 * t2), e33 = exp2f(qa3 * t3);
            den0 += (e00 + e01) + (e02 + e03);
            den1 += (e10 + e11) + (e12 + e13);
            den2 += (e20 + e21) + (e22 + e23);
            den3 += (e30 + e31) + (e32 + e33);
            wa0 = fmaf(e00, t0, fmaf(e01, t1, fmaf(e02, t2, fmaf(e03, t3, wa0))));
            wa1 = fmaf(e10, t0, fmaf(e11, t1, fmaf(e12, t2, fmaf(e13, t3, wa1))));
            wa2 = fmaf(e20, t0, fmaf(e21, t1, fmaf(e22, t2, fmaf(e23, t3, wa2))));
            wa3 = fmaf(e30, t0, fmaf(e31, t1, fmaf(e32, t2, fmaf(e33, t3, wa3))));
        }
        const int it = ib + (nq << 2), rem = cnt & 3;
        for (int j = 0; j < rem; ++j) {
            int cc = s_csr[it + j];
            float t0 = *(const float*)(featg + cc);
            float e0 = exp2f(qa0 * t0), e1 = exp2f(qa1 * t0);
            float e2 = exp2f(qa2 * t0), e3 = exp2f(qa3 * t0);
            den0 += e0; den1 += e1; den2 += e2; den3 += e3;
            wa0 = fmaf(e0, t0, wa0); wa1 = fmaf(e1, t0, wa1);
            wa2 = fmaf(e2, t0, wa2); wa3 = fmaf(e3, t0, wa3);
        }
        float y0 = LREL(fmaf(V1W0, wa0 / den0, V1B0) + fmaf(xv, S1W0, S1B0));
        float y1 = LREL(fmaf(V1W1, wa1 / den1, V1B1) + fmaf(xv, S1W1, S1B1));
        float y2 = LREL(fmaf(V1W2, wa2 / den2, V1B2) + fmaf(xv, S1W2, S1B2));
        float y3 = LREL(fmaf(V1W3, wa3 / den3, V1B3) + fmaf(xv, S1W3, S1B3));
        y_q[k]  = Q2B + y0 * Q2W0 + y1 * Q2W1 + y2 * Q2W2 + y3 * Q2W3;
        y_sk[k] = S2B + y0 * S2W0 + y1 * S2W1 + y2 * S2W2 + y3 * S2W3;
        if (act) {
            float k2v = K2B + y0 * K2W0 + y1 * K2W1 + y2 * K2W2 + y3 * K2W3;
            float v2v = V2B + y0 * V2W0 + y1 * V2W1 + y2 * V2W2 + y3 * V2W3;
            float k2L = k2v * LOG2E;
            s_kv[n * PADS + g] = make_float2(k2L, v2v);
            kmaxl = fmaxf(kmaxl, fabsf(k2L));
        }
    }
    // per-graph K-infinity: combine wave's 2 r-streams, then 16 wave partials
    kmaxl = fmaxf(kmaxl, __shfl_xor(kmaxl, 32, 64));
    if (lane < 32) s_kwave[w * PADS + g] = kmaxl;
    __syncthreads();
    float kinf = 0.0f;
#pragma unroll
    for (int i = 0; i < NWAVE; ++i) kinf = fmaxf(kinf, s_kwave[i * PADS + g]);

    // ---- TransformerConv 2 (H=1,C=1): single fused pass, shift = |q|*kinf ----
    float zs = 0, zq = 0;
#pragma unroll
    for (int k = 0; k < NI; ++k) {
        const int n = nodes[k];
        const int slot = k * ROWS + r;
        const int cnt  = s_scnt[slot];
        const int ib   = s_sbeg[slot];
        const bool act = n >= 0;
        const float q = y_q[k];
        float zz = 0.0f;
        if (act) {
            const float ml = fabsf(q) * kinf;     // upper bound: q*kvx <= ml
            const int nq = cnt >> 2, rem = cnt & 3;
            float den = 0, acc = 0;
            for (int t = 0; t < nq; ++t) {
                int4 c = *(const int4*)(s_csr + ib + (t << 2));
                float2 kv0 = *(const float2*)(kvg + (c.x << 1));
                float2 kv1 = *(const float2*)(kvg + (c.y << 1));
                float2 kv2 = *(const float2*)(kvg + (c.z << 1));
                float2 kv3 = *(const float2*)(kvg + (c.w << 1));
                float e0 = exp2f(fmaf(q, kv0.x, -ml));
                float e1 = exp2f(fmaf(q, kv1.x, -ml));
                float e2 = exp2f(fmaf(q, kv2.x, -ml));
                float e3 = exp2f(fmaf(q, kv3.x, -ml));
                den += (e0 + e1) + (e2 + e3);
                acc = fmaf(e0, kv0.y, fmaf(e1, kv1.y, fmaf(e2, kv2.y, fmaf(e3, kv3.y, acc))));
            }
            const int it = ib + (nq << 2);
            for (int j = 0; j < rem; ++j) {
                float2 kv0 = *(const float2*)(kvg + (s_csr[it + j] << 1));
                float e0 = exp2f(fmaf(q, kv0.x, -ml));
                den += e0;
                acc = fmaf(e0, kv0.y, acc);
            }
            zz = LREL(acc / den + y_sk[k]);
            zs += zz; zq = fmaf(zz, zz, zq);
        }
        z[k] = zz;
    }

    // ---- final LayerNorm(78) + classifier ----
    zs += __shfl_xor(zs, 32, 64);
    zq += __shfl_xor(zq, 32, 64);
    if (lane < 32) {
        s_redA[w * PADS + g] = zs;
        s_redB[w * PADS + g] = zq;
    }
    __syncthreads();
    if (tid < GPB) {
        float a = 0, bb = 0;
#pragma unroll
        for (int i = 0; i < NWAVE; ++i) {
            a  += s_redA[i * PADS + tid];
            bb += s_redB[i * PADS + tid];
        }
        float mean = a * (1.0f / 78.0f);
        float var  = bb * (1.0f / 78.0f) - mean * mean;
        s_statM[tid] = mean;
        s_statR[tid] = rsqrtf(var + 1e-5f);
    }
    __syncthreads();
    float mean = s_statM[g], rstd = s_statR[g];
    float p0 = 0, p1 = 0;
#pragma unroll
    for (int k = 0; k < NI; ++k) {
        int n = nodes[k];
        if (n >= 0) {
            float zn = fmaf((z[k] - mean) * rstd, ln2g[n], ln2b[n]);
            p0 = fmaf(zn, clsw[n], p0);
            p1 = fmaf(zn, clsw[NNODE + n], p1);
        }
    }
    p0 += __shfl_xor(p0, 32, 64);
    p1 += __shfl_xor(p1, 32, 64);
    __syncthreads();
    if (lane < 32) {
        s_redA[w * PADS + g] = p0;
        s_redB[w * PADS + g] = p1;
    }
    __syncthreads();
    if (tid < GPB) {
        float a = 0, bb = 0;
#pragma unroll
        for (int i = 0; i < NWAVE; ++i) {
            a  += s_redA[i * PADS + tid];
            bb += s_redB[i * PADS + tid];
        }
        long gi = base + tid;
        if (gi < Bn) {
            out[gi * 2 + 0] = a + clsb[0];
            out[gi * 2 + 1] = bb + clsb[1];
        }
    }
}

// ---------------------------------------------------------------------------
extern "C" void kernel_launch(void* const* d_in, const int* in_sizes, int n_in,
                              void* d_out, int out_size, void* d_ws, size_t ws_size,
                              hipStream_t stream) {
    const float* cli   = (const float*)d_in[0];
    const float* radio = (const float*)d_in[1];
    const int*   ei    = (const int*)d_in[2];
    const float* ln1g = (const float*)d_in[3];
    const float* ln1b = (const float*)d_in[4];
    const float* encw = (const float*)d_in[5];
    const float* encb = (const float*)d_in[6];
    const float* q1w  = (const float*)d_in[7];
    const float* q1b  = (const float*)d_in[8];
    const float* k1w  = (const float*)d_in[9];
    const float* k1b  = (const float*)d_in[10];
    const float* v1w  = (const float*)d_in[11];
    const float* v1b  = (const float*)d_in[12];
    const float* s1w  = (const float*)d_in[13];
    const float* s1b  = (const float*)d_in[14];
    const float* q2w  = (const float*)d_in[15];
    const float* q2b  = (const float*)d_in[16];
    const float* k2w  = (const float*)d_in[17];
    const float* k2b  = (const float*)d_in[18];
    const float* v2w  = (const float*)d_in[19];
    const float* v2b  = (const float*)d_in[20];
    const float* s2w  = (const float*)d_in[21];
    const float* s2b  = (const float*)d_in[22];
    const float* ln2g = (const float*)d_in[23];
    const float* ln2b = (const float*)d_in[24];
    const float* clsw = (const float*)d_in[25];
    const float* clsb = (const float*)d_in[26];

    const int E  = in_sizes[2] / 2;
    const int Bn = in_sizes[0] / 58;

    int* slot_node = (int*)d_ws;                  // 96
    int* slot_beg  = slot_node + 96;              // 97 (pad to 104)
    int* slot_cnt  = slot_beg + 104;              // 96
    int* csr2      = slot_cnt + 96;               // <= E + 3*NSLOT
    int  csr_cap   = E + 3 * NSLOT + 8;
    float* h       = (float*)(csr2 + ((csr_cap + 7) & ~7));

    build_csr_kernel<<<1, 256, 0, stream>>>(ei, E, slot_node, slot_beg,
                                            slot_cnt, csr2);

    const int egrid = (Bn + 15) / 16;
    encode_kernel<<<egrid, 256, 0, stream>>>(radio, ln1g, ln1b, encw, encb, Bn, h);

    const int grid = (Bn + GPB - 1) / GPB;
    size_t shmem = (size_t)csr_cap * sizeof(int);
    graph_conv_kernel<<<grid, BLOCK, shmem, stream>>>(
        cli, h,
        q1w, q1b, k1w, k1b, v1w, v1b, s1w, s1b,
        q2w, q2b, k2w, k2b, v2w, v2b, s2w, s2b,
        ln2g, ln2b, clsw, clsb,
        slot_node, slot_beg, slot_cnt, csr2, Bn, (float*)d_out);
}